// Round 1
// baseline (160.543 us; speedup 1.0000x reference)
//
#include <hip/hip_runtime.h>

#define T_SEQ 2048
#define NH 4
#define DH 64

typedef __bf16 bf16x8 __attribute__((ext_vector_type(8)));
typedef float f32x4 __attribute__((ext_vector_type(4)));

__device__ __forceinline__ unsigned short f2bf_rne(float x) {
  unsigned int u = __builtin_bit_cast(unsigned int, x);
  u += 0x7fffu + ((u >> 16) & 1u);
  return (unsigned short)(u >> 16);
}

__device__ __forceinline__ void async_cp16(const unsigned short* g, unsigned short* l) {
  __builtin_amdgcn_global_load_lds(
      (const __attribute__((address_space(1))) unsigned int*)g,
      (__attribute__((address_space(3))) unsigned int*)l, 16, 0, 0);
}

// ---------------------------------------------------------------------------
// Kernel A: Wh = h @ W (fp32 compute).
// Writes Kb[bh][t][d] = bf16(Wh * sqrt(log2e/8))  (used as both Q and K)
//        Vt[bh][d][t] = bf16(Wh)                  (PV B-operand layout)
// ---------------------------------------------------------------------------
__global__ __launch_bounds__(256, 2) void wh_gemm(
    const float* __restrict__ h, const float* __restrict__ W,
    unsigned short* __restrict__ Kb, unsigned short* __restrict__ Vt) {
  __shared__ __align__(16) float hs[32 * 256];
  const int tid = threadIdx.x;
  const int mbase = blockIdx.x * 32;
  const float4* hblk = (const float4*)(h + (size_t)mbase * 256);
#pragma unroll
  for (int i = 0; i < 8; i++) {
    int slot = i * 256 + tid;
    ((float4*)hs)[slot] = hblk[slot];
  }
  __syncthreads();
  const int nid = tid & 63;   // 4 output cols per thread: n = 4*nid..4*nid+3
  const int rg = tid >> 6;    // wave: rows rg*8 .. rg*8+7
  float acc[8][4];
#pragma unroll
  for (int r = 0; r < 8; r++)
#pragma unroll
    for (int j = 0; j < 4; j++) acc[r][j] = 0.f;
  const float4* Wv = (const float4*)W;
  for (int k = 0; k < 256; k += 2) {
    float4 w0 = Wv[k * 64 + nid];
    float4 w1 = Wv[(k + 1) * 64 + nid];
#pragma unroll
    for (int r = 0; r < 8; r++) {
      float2 hv = *(const float2*)&hs[(rg * 8 + r) * 256 + k];
      acc[r][0] += hv.x * w0.x; acc[r][1] += hv.x * w0.y;
      acc[r][2] += hv.x * w0.z; acc[r][3] += hv.x * w0.w;
      acc[r][0] += hv.y * w1.x; acc[r][1] += hv.y * w1.y;
      acc[r][2] += hv.y * w1.z; acc[r][3] += hv.y * w1.w;
    }
  }
  const float s1 = 0.424664717f;  // sqrt(log2(e)/8): Q and K each scaled -> S = log2e/8 * qk
  const int head = nid >> 4;
  const int d0 = (nid & 15) * 4;
#pragma unroll
  for (int r = 0; r < 8; r++) {
    int m = mbase + rg * 8 + r;
    int b = m >> 11, t = m & 2047;
    size_t bh = (size_t)(b * NH + head);
    ushort4 kp;
    kp.x = f2bf_rne(acc[r][0] * s1);
    kp.y = f2bf_rne(acc[r][1] * s1);
    kp.z = f2bf_rne(acc[r][2] * s1);
    kp.w = f2bf_rne(acc[r][3] * s1);
    *(ushort4*)&Kb[(bh * T_SEQ + t) * DH + d0] = kp;
    size_t vtb = (bh * DH + d0) * T_SEQ + t;
    Vt[vtb]             = f2bf_rne(acc[r][0]);
    Vt[vtb + T_SEQ]     = f2bf_rne(acc[r][1]);
    Vt[vtb + 2 * T_SEQ] = f2bf_rne(acc[r][2]);
    Vt[vtb + 3 * T_SEQ] = f2bf_rne(acc[r][3]);
  }
}

// ---------------------------------------------------------------------------
// Attention: per block = one (bh, 64-row q-tile). 4 waves, 16 q-rows/wave.
// No-max softmax (scores bounded ~20 in exp2 domain -> no overflow), so no
// running max / O rescale; l reduced once in epilogue.
// LDS K/V tiles use XOR chunk swizzle (source-permuted for global_load_lds).
// ---------------------------------------------------------------------------
__global__ __launch_bounds__(256, 4) void attn(
    const unsigned short* __restrict__ Kb, const unsigned short* __restrict__ Vt,
    float* __restrict__ out) {
  __shared__ __align__(16) unsigned short ldsK[64 * 64];     // [key][chunk-swz]
  __shared__ __align__(16) unsigned short ldsV[64 * 64];     // [d][chunk-swz]
  __shared__ __align__(16) unsigned short ldsP[4][16 * 64];  // per-wave P
  const int tid = threadIdx.x;
  const int wave = tid >> 6;
  const int lane = tid & 63;
  const int l15 = lane & 15;
  const int quad = lane >> 4;
  const int bh = blockIdx.x >> 5;
  const int qtile = blockIdx.x & 31;
  const unsigned short* Kbh = Kb + (size_t)bh * T_SEQ * DH;
  const unsigned short* Vbh = Vt + (size_t)bh * DH * T_SEQ;

  // A-frag Q: A[m=lane&15][k=quad*8+j], two 32-wide k-steps over D=64
  const int qrow = qtile * 64 + wave * 16 + l15;
  bf16x8 aq0 = *(const bf16x8*)&Kbh[qrow * DH + quad * 8];
  bf16x8 aq1 = *(const bf16x8*)&Kbh[qrow * DH + 32 + quad * 8];

  f32x4 o[4];
  float lsum[4];
#pragma unroll
  for (int i = 0; i < 4; i++) {
    o[i] = (f32x4){0.f, 0.f, 0.f, 0.f};
    lsum[i] = 0.f;
  }
  unsigned short* Pw = ldsP[wave];

  for (int kt = 0; kt < 32; kt++) {
    __syncthreads();  // prior iter's LDS reads done before overwrite
#pragma unroll
    for (int i = 0; i < 2; i++) {
      int slot = i * 256 + tid;            // 512 16B-slots per tile
      int r = slot >> 3;                   // row (key or d)
      int c = (slot & 7) ^ (r & 7);        // source chunk for swizzled slot
      unsigned short* lb = &ldsK[(i * 256 + wave * 64) * 8];  // wave-uniform base
      async_cp16(&Kbh[(kt * 64 + r) * DH + c * 8], lb);
      unsigned short* lbv = &ldsV[(i * 256 + wave * 64) * 8];
      async_cp16(&Vbh[(size_t)r * T_SEQ + kt * 64 + c * 8], lbv);
    }
    __syncthreads();  // drains vmcnt (global_load_lds) + barrier

    // S = Q K^T : B-frag B[k=quad*8+j][n=key(lane&15)] from swizzled ldsK
    f32x4 sfr[4];
#pragma unroll
    for (int nt = 0; nt < 4; nt++) {
      int key = nt * 16 + l15;
      bf16x8 kf0 = *(const bf16x8*)&ldsK[key * 64 + ((quad ^ (key & 7)) << 3)];
      bf16x8 kf1 = *(const bf16x8*)&ldsK[key * 64 + (((4 + quad) ^ (key & 7)) << 3)];
      f32x4 s = {0.f, 0.f, 0.f, 0.f};
      s = __builtin_amdgcn_mfma_f32_16x16x32_bf16(aq0, kf0, s, 0, 0, 0);
      s = __builtin_amdgcn_mfma_f32_16x16x32_bf16(aq1, kf1, s, 0, 0, 0);
      sfr[nt] = s;
    }

    // p = exp2(leaky(S)) (scale pre-folded); accumulate l; P -> LDS (trunc bf16)
#pragma unroll
    for (int nt = 0; nt < 4; nt++) {
      int col = nt * 16 + l15;
#pragma unroll
      for (int reg = 0; reg < 4; reg++) {
        float v = sfr[nt][reg];
        float e = __builtin_amdgcn_exp2f(fmaxf(v, 0.2f * v));
        lsum[reg] += e;
        int row = quad * 4 + reg;  // C-layout: row=(lane>>4)*4+reg, col=lane&15
        Pw[(row << 6) + (((((col >> 3) ^ (row & 7))) << 3) | (col & 7))] =
            (unsigned short)(__builtin_bit_cast(unsigned int, e) >> 16);
      }
    }
    __builtin_amdgcn_s_waitcnt(0xC07F);  // lgkmcnt(0): P writes land before reads

    // O += P V : A-frag from Pw round-trip, B-frag from swizzled ldsV
#pragma unroll
    for (int kc = 0; kc < 2; kc++) {
      bf16x8 ap = *(const bf16x8*)&Pw[(l15 << 6) + ((((kc << 2) + quad) ^ (l15 & 7)) << 3)];
#pragma unroll
      for (int nt = 0; nt < 4; nt++) {
        int d = nt * 16 + l15;
        bf16x8 vf = *(const bf16x8*)&ldsV[(d << 6) + ((((kc << 2) + quad) ^ (d & 7)) << 3)];
        o[nt] = __builtin_amdgcn_mfma_f32_16x16x32_bf16(ap, vf, o[nt], 0, 0, 0);
      }
    }
  }

  // epilogue: reduce l across the 16 lanes sharing each row group, normalize
  float inv[4];
#pragma unroll
  for (int reg = 0; reg < 4; reg++) {
    float l = lsum[reg];
    l += __shfl_xor(l, 1, 64);
    l += __shfl_xor(l, 2, 64);
    l += __shfl_xor(l, 4, 64);
    l += __shfl_xor(l, 8, 64);
    inv[reg] = 1.0f / l;
  }
  const int b = bh >> 2, head = bh & 3;
#pragma unroll
  for (int nt = 0; nt < 4; nt++) {
    int d = nt * 16 + l15;
#pragma unroll
    for (int reg = 0; reg < 4; reg++) {
      int trow = qtile * 64 + wave * 16 + quad * 4 + reg;
      out[((size_t)b * T_SEQ + trow) * 256 + head * 64 + d] = o[nt][reg] * inv[reg];
    }
  }
}

extern "C" void kernel_launch(void* const* d_in, const int* in_sizes, int n_in,
                              void* d_out, int out_size, void* d_ws, size_t ws_size,
                              hipStream_t stream) {
  const float* h = (const float*)d_in[0];
  const float* W = (const float*)d_in[1];
  float* out = (float*)d_out;
  // workspace: Kb 8 MB (32*2048*64 bf16) + Vt 8 MB
  unsigned short* Kb = (unsigned short*)d_ws;
  unsigned short* Vt = Kb + (size_t)32 * T_SEQ * DH;
  wh_gemm<<<512, 256, 0, stream>>>(h, W, Kb, Vt);
  attn<<<32 * 32, 256, 0, stream>>>(Kb, Vt, out);
}